// Round 3
// baseline (114.169 us; speedup 1.0000x reference)
//
#include <hip/hip_runtime.h>
#include <math.h>

#define NB 16
#define TQ 2048
#define TK 2048
#define DD 128
#define DVV 128

constexpr int QTILE = 64;   // q rows per block (4 waves x 16)
constexpr int KTILE = 64;   // k/v rows per iteration

#define KSTR (DD + 8)       // 136 halfs = 272B row stride
#define VSTR (KTILE + 8)    // 72 halfs = 144B
#define PSTR (KTILE + 8)    // 72 halfs = 144B

typedef __attribute__((ext_vector_type(8))) _Float16 half8;
typedef __attribute__((ext_vector_type(4))) _Float16 half4;
typedef __attribute__((ext_vector_type(2))) _Float16 half2v;
typedef __attribute__((ext_vector_type(4))) float f32x4;

__device__ inline float fast_exp2(float x) {
#if __has_builtin(__builtin_amdgcn_exp2f)
    return __builtin_amdgcn_exp2f(x);
#else
    return exp2f(x);
#endif
}

// ---------------- attention pass: one (b, q-tile, k-split) per block ----------------
__global__ __launch_bounds__(256)
void attn_fwd(const float* __restrict__ qg, const float* __restrict__ kgl,
              const float* __restrict__ vg, const int* __restrict__ vlg,
              float* __restrict__ outg, float* __restrict__ wso,
              float* __restrict__ wsml, int ns)
{
    __shared__ _Float16 Klds[KTILE][KSTR];       // 17408 B
    __shared__ _Float16 VTlds[DVV][VSTR];        // 18432 B
    __shared__ _Float16 Plds[4][16][PSTR];       //  9216 B

    const int tid  = threadIdx.x;
    const int wid  = tid >> 6;
    const int lane = tid & 63;
    const int l15  = lane & 15;
    const int lhi  = lane >> 4;

    const int bid   = blockIdx.x;
    const int b     = bid & (NB - 1);
    const int qbase = (bid >> 4) * QTILE;
    const int s     = blockIdx.y;

    const int VL  = vlg[b];
    const int nkt = (VL + KTILE - 1) / KTILE;
    const int tps = (nkt + ns - 1) / ns;
    const int t0  = s * tps;
    const int t1  = min(nkt, t0 + tps);
    if (t0 >= t1) return;                        // empty split (before any barrier)

    const float* kbase = kgl + (size_t)b * TK * DD;
    const float* vbase = vg  + (size_t)b * TK * DVV;

    // ---- Q fragments, scale * log2e folded (softmax in log2 domain) ----
    half8 qf[4];
    {
        const float scale = 0.08838834764831845f * 1.4426950408889634f;
        const int qrow = qbase + wid * 16 + l15;
        const float* qp = qg + (size_t)(b * TQ + qrow) * DD + lhi * 8;
#pragma unroll
        for (int c = 0; c < 4; ++c) {
            float4 f0 = *(const float4*)(qp + c * 32);
            float4 f1 = *(const float4*)(qp + c * 32 + 4);
            half8 t;
            t[0] = (_Float16)(f0.x * scale); t[1] = (_Float16)(f0.y * scale);
            t[2] = (_Float16)(f0.z * scale); t[3] = (_Float16)(f0.w * scale);
            t[4] = (_Float16)(f1.x * scale); t[5] = (_Float16)(f1.y * scale);
            t[6] = (_Float16)(f1.z * scale); t[7] = (_Float16)(f1.w * scale);
            qf[c] = t;
        }
    }

    // ---- staging geometry ----
    const int krow0 = tid >> 5;          // K row = krow0 + p*8
    const int kcol  = (tid * 4) & 127;
    const int vd    = tid & 127;         // V: d-major coalesced dword loads
    const int vk0   = (tid >> 7) * 32;
    const int va    = (vd >> 3) & 7;     // k-rotation: spreads LDS write banks

    float4 kreg[8];
    float  vr0[16], vr1[16];

    auto issue_stage = [&](int kb) {
#pragma unroll
        for (int p = 0; p < 8; ++p)
            kreg[p] = *(const float4*)(kbase + (size_t)(kb + krow0 + p * 8) * DD + kcol);
#pragma unroll
        for (int kp = 0; kp < 16; ++kp) {
            int kk = vk0 + 2 * ((kp + va) & 15);
            vr0[kp] = vbase[(size_t)(kb + kk)     * DVV + vd];
            vr1[kp] = vbase[(size_t)(kb + kk + 1) * DVV + vd];
        }
    };
    auto write_stage = [&]() {
#pragma unroll
        for (int p = 0; p < 8; ++p) {
            half4 h;
            h[0] = (_Float16)kreg[p].x; h[1] = (_Float16)kreg[p].y;
            h[2] = (_Float16)kreg[p].z; h[3] = (_Float16)kreg[p].w;
            *(half4*)&Klds[krow0 + p * 8][kcol] = h;
        }
#pragma unroll
        for (int kp = 0; kp < 16; ++kp) {
            int kk = vk0 + 2 * ((kp + va) & 15);
            half2v h; h[0] = (_Float16)vr0[kp]; h[1] = (_Float16)vr1[kp];
            *(half2v*)&VTlds[vd][kk] = h;
        }
    };

    float m_i = -INFINITY, l_i = 0.f;
    f32x4 o[8];
#pragma unroll
    for (int n = 0; n < 8; ++n) { f32x4 z = {0.f, 0.f, 0.f, 0.f}; o[n] = z; }

    issue_stage(t0 * KTILE);
    write_stage();
    __syncthreads();

    for (int t = t0; t < t1; ++t) {
        const int kb = t * KTILE;
        const bool pre = (t + 1 < t1);
        if (pre) issue_stage(kb + KTILE);

        // ---- S^T = K Q^T ----
        f32x4 sc[4];
#pragma unroll
        for (int ct = 0; ct < 4; ++ct) {
            f32x4 z = {0.f, 0.f, 0.f, 0.f};
            sc[ct] = z;
#pragma unroll
            for (int c = 0; c < 4; ++c) {
                half8 kf = *(const half8*)&Klds[ct * 16 + l15][c * 32 + lhi * 8];
                sc[ct] = __builtin_amdgcn_mfma_f32_16x16x32_f16(kf, qf[c], sc[ct], 0, 0, 0);
            }
        }
        // ---- mask k rows >= VL (boundary tile only) ----
        if (kb + KTILE > VL) {
#pragma unroll
            for (int ct = 0; ct < 4; ++ct) {
                const int kg = kb + ct * 16 + lhi * 4;
#pragma unroll
                for (int r = 0; r < 4; ++r)
                    if (kg + r >= VL) sc[ct][r] = -1e30f;
            }
        }

        // ---- per-lane online softmax (q = l15) ----
        float mx = sc[0][0];
#pragma unroll
        for (int ct = 0; ct < 4; ++ct)
#pragma unroll
            for (int r = 0; r < 4; ++r) mx = fmaxf(mx, sc[ct][r]);
        mx = fmaxf(mx, __shfl_xor(mx, 16));
        mx = fmaxf(mx, __shfl_xor(mx, 32));

        const bool skip = __all(mx <= m_i + 8.0f);
        const float mnew = skip ? m_i : fmaxf(m_i, mx);

        float p[16];
        float sum = 0.f;
#pragma unroll
        for (int ct = 0; ct < 4; ++ct)
#pragma unroll
            for (int r = 0; r < 4; ++r) {
                float e = fast_exp2(sc[ct][r] - mnew);
                p[ct * 4 + r] = e;
                sum += e;
            }
        sum += __shfl_xor(sum, 16);
        sum += __shfl_xor(sum, 32);

#pragma unroll
        for (int ct = 0; ct < 4; ++ct) {
            half4 ph;
            ph[0] = (_Float16)p[ct * 4 + 0]; ph[1] = (_Float16)p[ct * 4 + 1];
            ph[2] = (_Float16)p[ct * 4 + 2]; ph[3] = (_Float16)p[ct * 4 + 3];
            *(half4*)&Plds[wid][l15][ct * 16 + lhi * 4] = ph;
        }

        if (skip) {
            l_i += sum;
        } else {
            const float corr = fast_exp2(m_i - mnew);
            l_i = l_i * corr + sum;
            m_i = mnew;
            float cr[4];
#pragma unroll
            for (int r = 0; r < 4; ++r)
                cr[r] = __shfl(corr, (lane & 48) | (lhi * 4 + r));
#pragma unroll
            for (int n = 0; n < 8; ++n)
#pragma unroll
                for (int r = 0; r < 4; ++r) o[n][r] *= cr[r];
        }

        // ---- O += P V ----
        half8 pa0 = *(const half8*)&Plds[wid][l15][lhi * 8];
        half8 pa1 = *(const half8*)&Plds[wid][l15][32 + lhi * 8];
#pragma unroll
        for (int n = 0; n < 8; ++n) {
            half8 vb0 = *(const half8*)&VTlds[n * 16 + l15][lhi * 8];
            half8 vb1 = *(const half8*)&VTlds[n * 16 + l15][32 + lhi * 8];
            o[n] = __builtin_amdgcn_mfma_f32_16x16x32_f16(pa0, vb0, o[n], 0, 0, 0);
            o[n] = __builtin_amdgcn_mfma_f32_16x16x32_f16(pa1, vb1, o[n], 0, 0, 0);
        }

        __syncthreads();
        if (pre) write_stage();
        __syncthreads();
    }

    if (ns == 1) {
        // single-pass: normalize + store to out
        float li4[4];
#pragma unroll
        for (int r = 0; r < 4; ++r) {
            float lr = __shfl(l_i, (lane & 48) | (lhi * 4 + r));
            li4[r] = 1.0f / lr;
        }
#pragma unroll
        for (int r = 0; r < 4; ++r) {
            const int qrow = qbase + wid * 16 + lhi * 4 + r;
            float* op = outg + (size_t)(b * TQ + qrow) * DVV + l15;
#pragma unroll
            for (int n = 0; n < 8; ++n)
                op[n * 16] = o[n][r] * li4[r];
        }
    } else {
        // write unnormalized partial + (m, l)
        if (lhi == 0) {
            float2 ml = make_float2(m_i, l_i);
            *(float2*)&wsml[((size_t)(s * NB + b) * TQ + qbase + wid * 16 + l15) * 2] = ml;
        }
        float* po = wso + ((size_t)(s * NB + b) * TQ + qbase + wid * 16) * DVV;
#pragma unroll
        for (int r = 0; r < 4; ++r)
#pragma unroll
            for (int n = 0; n < 8; ++n)
                po[(lhi * 4 + r) * DVV + n * 16 + l15] = o[n][r];
    }
}

// ---------------- combine pass: softmax-weighted merge of splits ----------------
__global__ __launch_bounds__(256)
void attn_combine(const float* __restrict__ wso, const float* __restrict__ wsml,
                  const int* __restrict__ vlg, float* __restrict__ outg, int ns)
{
    const int idx = blockIdx.x * 256 + threadIdx.x;   // B*TQ*(DVV/4) = 1M
    const int d4 = idx & 31;
    const int q  = (idx >> 5) & (TQ - 1);
    const int b  = idx >> 16;

    const int VL  = vlg[b];
    const int nkt = (VL + KTILE - 1) / KTILE;
    const int tps = (nkt + ns - 1) / ns;
    const int nv  = (nkt + tps - 1) / tps;            // valid splits

    float M = -1e30f, den = 0.f;
    f32x4 acc = {0.f, 0.f, 0.f, 0.f};
    for (int s = 0; s < nv; ++s) {
        const size_t row = (size_t)(s * NB + b) * TQ + q;
        float2 ml = *(const float2*)&wsml[row * 2];
        float Mn = fmaxf(M, ml.x);
        float c  = fast_exp2(M - Mn);
        float w  = fast_exp2(ml.x - Mn);
        f32x4 ov = *(const f32x4*)&wso[row * DVV + d4 * 4];
        acc = acc * c + ov * w;
        den = den * c + w * ml.y;
        M = Mn;
    }
    const float inv = 1.0f / den;
    f32x4 r = acc * inv;
    *(f32x4*)&outg[((size_t)b * TQ + q) * DVV + d4 * 4] = r;
}

extern "C" void kernel_launch(void* const* d_in, const int* in_sizes, int n_in,
                              void* d_out, int out_size, void* d_ws, size_t ws_size,
                              hipStream_t stream) {
    const float* q  = (const float*)d_in[0];
    const float* k  = (const float*)d_in[1];
    const float* v  = (const float*)d_in[2];
    const int*   vl = (const int*)d_in[3];
    float* out = (float*)d_out;

    const size_t o_elems  = (size_t)NB * TQ * DVV;       // per split
    const size_t ml_elems = (size_t)NB * TQ * 2;         // per split
    const size_t per_split = (o_elems + ml_elems) * sizeof(float);

    int ns = 1;
    if (ws_size >= 4 * per_split) ns = 4;
    else if (ws_size >= 2 * per_split) ns = 2;

    float* wso  = (float*)d_ws;
    float* wsml = wso + (size_t)ns * o_elems;

    dim3 grid(NB * (TQ / QTILE), ns);
    hipLaunchKernelGGL(attn_fwd, grid, dim3(256), 0, stream,
                       q, k, v, vl, out, wso, wsml, ns);

    if (ns > 1) {
        dim3 cgrid((NB * TQ * (DVV / 4)) / 256);
        hipLaunchKernelGGL(attn_combine, cgrid, dim3(256), 0, stream,
                           wso, wsml, vl, out, ns);
    }
}

// Round 5
// 98.236 us; speedup vs baseline: 1.1622x; 1.1622x over previous
//
#include <hip/hip_runtime.h>
#include <math.h>

#define NB 16
#define TQ 2048
#define TK 2048
#define DD 128
#define DVV 128

constexpr int QTILE = 64;   // q rows per block (4 waves x 16)
constexpr int KTILE = 32;   // k/v rows per iteration (double-buffered)

#define KSTR 136            // halfs, 272B row stride (K tile)
#define VSTR 40             // halfs,  80B row stride (V^T tile)
#define PSTR 40

typedef __attribute__((ext_vector_type(8))) _Float16 half8;
typedef __attribute__((ext_vector_type(4))) _Float16 half4;
typedef __attribute__((ext_vector_type(4))) float f32x4;
typedef __attribute__((ext_vector_type(2))) float f32x2;

__device__ inline float fast_exp2(float x) {
#if __has_builtin(__builtin_amdgcn_exp2f)
    return __builtin_amdgcn_exp2f(x);
#else
    return exp2f(x);
#endif
}

__device__ inline void setprio1() {
#if __has_builtin(__builtin_amdgcn_s_setprio)
    __builtin_amdgcn_s_setprio(1);
#endif
}
__device__ inline void setprio0() {
#if __has_builtin(__builtin_amdgcn_s_setprio)
    __builtin_amdgcn_s_setprio(0);
#endif
}

// ---------------- attention pass: one (b, q-tile, k-split) per block ----------------
__global__ __launch_bounds__(256, 3)
void attn_fwd(const float* __restrict__ qg, const float* __restrict__ kgl,
              const float* __restrict__ vg, const int* __restrict__ vlg,
              float* __restrict__ outg, float* __restrict__ wso,
              float* __restrict__ wsml, int ns)
{
    __shared__ _Float16 Klds[2][KTILE][KSTR];    // 2 x 8704 B
    __shared__ _Float16 VTlds[2][DVV][VSTR];     // 2 x 10240 B
    __shared__ _Float16 Plds[4][16][PSTR];       // 5120 B          total 43008 B

    const int tid  = threadIdx.x;
    const int wid  = tid >> 6;
    const int lane = tid & 63;
    const int l15  = lane & 15;
    const int lhi  = lane >> 4;

    const int bid   = blockIdx.x;
    const int b     = bid & (NB - 1);
    const int qbase = (bid >> 4) * QTILE;
    const int sp    = blockIdx.y;

    const int VL  = vlg[b];
    const int nkt = (VL + KTILE - 1) / KTILE;
    const int tps = (nkt + ns - 1) / ns;
    const int t0  = sp * tps;
    const int t1  = min(nkt, t0 + tps);
    if (t0 >= t1) return;                        // empty split (before any barrier)

    const float* kbase = kgl + (size_t)b * TK * DD;
    const float* vbase = vg  + (size_t)b * TK * DVV;

    // ---- Q fragments, scale * log2e folded (softmax in log2 domain) ----
    half8 qf[4];
    {
        const float scale = 0.08838834764831845f * 1.4426950408889634f;
        const int qrow = qbase + wid * 16 + l15;
        const float* qp = qg + (size_t)(b * TQ + qrow) * DD + lhi * 8;
#pragma unroll
        for (int c = 0; c < 4; ++c) {
            float4 f0 = *(const float4*)(qp + c * 32);
            float4 f1 = *(const float4*)(qp + c * 32 + 4);
            half8 t;
            t[0] = (_Float16)(f0.x * scale); t[1] = (_Float16)(f0.y * scale);
            t[2] = (_Float16)(f0.z * scale); t[3] = (_Float16)(f0.w * scale);
            t[4] = (_Float16)(f1.x * scale); t[5] = (_Float16)(f1.y * scale);
            t[6] = (_Float16)(f1.z * scale); t[7] = (_Float16)(f1.w * scale);
            qf[c] = t;
        }
    }

    // ---- staging geometry ----
    const int krow = tid >> 5;            // K row = krow + p*8, p=0..3
    const int kcol = (tid & 31) * 4;      // K col (floats)
    const int vd   = (tid & 63) * 2;      // V: d-pair
    const int vk0  = ((tid >> 6) & 3) * 8;// k-octet per 64-thread group

    float4 sk[4];
    f32x2  sv[8];

    auto ISSUE = [&](int kb) {
#pragma unroll
        for (int p = 0; p < 4; ++p)
            sk[p] = *(const float4*)(kbase + (size_t)(kb + krow + p * 8) * DD + kcol);
#pragma unroll
        for (int j = 0; j < 8; ++j)
            sv[j] = *(const f32x2*)(vbase + (size_t)(kb + vk0 + j) * DVV + vd);
    };
    auto COMMIT = [&](int buf) {
#pragma unroll
        for (int p = 0; p < 4; ++p) {
            half4 h;
            h[0] = (_Float16)sk[p].x; h[1] = (_Float16)sk[p].y;
            h[2] = (_Float16)sk[p].z; h[3] = (_Float16)sk[p].w;
            *(half4*)&Klds[buf][krow + p * 8][kcol] = h;
        }
        half8 a, c;
#pragma unroll
        for (int j = 0; j < 8; ++j) {
            a[j] = (_Float16)sv[j].x;
            c[j] = (_Float16)sv[j].y;
        }
        *(half8*)&VTlds[buf][vd][vk0]     = a;
        *(half8*)&VTlds[buf][vd + 1][vk0] = c;
    };

    float m_i = -INFINITY, l_i = 0.f;
    f32x4 o[8];
#pragma unroll
    for (int n = 0; n < 8; ++n) { f32x4 z = {0.f, 0.f, 0.f, 0.f}; o[n] = z; }

    ISSUE(t0 * KTILE);
    COMMIT(0);
    __syncthreads();

    int cur = 0;
    for (int t = t0; t < t1; ++t) {
        const int kb = t * KTILE;
        const bool pre = (t + 1 < t1);
        if (pre) ISSUE(kb + KTILE);          // latency spans whole compute phase

        // ---- S^T = K Q^T : rows k (ct*16 + lhi*4+r), cols q (l15) ----
        f32x4 sc[2];
        setprio1();
#pragma unroll
        for (int ct = 0; ct < 2; ++ct) {
            f32x4 z = {0.f, 0.f, 0.f, 0.f};
            sc[ct] = z;
#pragma unroll
            for (int c = 0; c < 4; ++c) {
                half8 kf = *(const half8*)&Klds[cur][ct * 16 + l15][c * 32 + lhi * 8];
                sc[ct] = __builtin_amdgcn_mfma_f32_16x16x32_f16(kf, qf[c], sc[ct], 0, 0, 0);
            }
        }
        setprio0();

        // ---- mask k rows >= VL (boundary tile only) ----
        if (kb + KTILE > VL) {
#pragma unroll
            for (int ct = 0; ct < 2; ++ct) {
                const int kg = kb + ct * 16 + lhi * 4;
#pragma unroll
                for (int r = 0; r < 4; ++r)
                    if (kg + r >= VL) sc[ct][r] = -1e30f;
            }
        }

        // ---- per-lane online softmax (q = l15): 8 in-lane + 2 shuffles ----
        float mx = sc[0][0];
#pragma unroll
        for (int ct = 0; ct < 2; ++ct)
#pragma unroll
            for (int r = 0; r < 4; ++r) mx = fmaxf(mx, sc[ct][r]);
        mx = fmaxf(mx, __shfl_xor(mx, 16));
        mx = fmaxf(mx, __shfl_xor(mx, 32));

        const bool skip = __all(mx <= m_i + 8.0f);   // defer-max (log2 domain)
        const float mnew = skip ? m_i : fmaxf(m_i, mx);

        float p[8];
        float sum = 0.f;
#pragma unroll
        for (int ct = 0; ct < 2; ++ct)
#pragma unroll
            for (int r = 0; r < 4; ++r) {
                float e = fast_exp2(sc[ct][r] - mnew);
                p[ct * 4 + r] = e;
                sum += e;
            }
        sum += __shfl_xor(sum, 16);
        sum += __shfl_xor(sum, 32);

        // write P^T-layout [q][k]
#pragma unroll
        for (int ct = 0; ct < 2; ++ct) {
            half4 ph;
            ph[0] = (_Float16)p[ct * 4 + 0]; ph[1] = (_Float16)p[ct * 4 + 1];
            ph[2] = (_Float16)p[ct * 4 + 2]; ph[3] = (_Float16)p[ct * 4 + 3];
            *(half4*)&Plds[wid][l15][ct * 16 + lhi * 4] = ph;
        }

        if (skip) {
            l_i += sum;
        } else {
            const float corr = fast_exp2(m_i - mnew);
            l_i = l_i * corr + sum;
            m_i = mnew;
            float cr[4];
#pragma unroll
            for (int r = 0; r < 4; ++r)
                cr[r] = __shfl(corr, (lane & 48) | (lhi * 4 + r));
#pragma unroll
            for (int n = 0; n < 8; ++n)
#pragma unroll
                for (int r = 0; r < 4; ++r) o[n][r] *= cr[r];
        }

        // ---- O += P V ----
        half8 pa = *(const half8*)&Plds[wid][l15][lhi * 8];
        setprio1();
#pragma unroll
        for (int n = 0; n < 8; ++n) {
            half8 vb = *(const half8*)&VTlds[cur][n * 16 + l15][lhi * 8];
            o[n] = __builtin_amdgcn_mfma_f32_16x16x32_f16(pa, vb, o[n], 0, 0, 0);
        }
        setprio0();

        if (pre) COMMIT(cur ^ 1);            // vmcnt drained here only
        __syncthreads();
        cur ^= 1;
    }

    if (ns == 1) {
        float li4[4];
#pragma unroll
        for (int r = 0; r < 4; ++r) {
            float lr = __shfl(l_i, (lane & 48) | (lhi * 4 + r));
            li4[r] = 1.0f / lr;
        }
#pragma unroll
        for (int r = 0; r < 4; ++r) {
            const int qrow = qbase + wid * 16 + lhi * 4 + r;
            float* op = outg + (size_t)(b * TQ + qrow) * DVV + l15;
#pragma unroll
            for (int n = 0; n < 8; ++n)
                op[n * 16] = o[n][r] * li4[r];
        }
    } else {
        if (lhi == 0) {
            float2 ml = make_float2(m_i, l_i);
            *(float2*)&wsml[((size_t)(sp * NB + b) * TQ + qbase + wid * 16 + l15) * 2] = ml;
        }
        float* po = wso + ((size_t)(sp * NB + b) * TQ + qbase + wid * 16) * DVV;
#pragma unroll
        for (int r = 0; r < 4; ++r)
#pragma unroll
            for (int n = 0; n < 8; ++n)
                po[(lhi * 4 + r) * DVV + n * 16 + l15] = o[n][r];
    }
}

// ---------------- combine pass: softmax-weighted merge of splits ----------------
__global__ __launch_bounds__(256)
void attn_combine(const float* __restrict__ wso, const float* __restrict__ wsml,
                  const int* __restrict__ vlg, float* __restrict__ outg, int ns)
{
    const int idx = blockIdx.x * 256 + threadIdx.x;   // B*TQ*(DVV/4)
    const int d4 = idx & 31;
    const int q  = (idx >> 5) & (TQ - 1);
    const int b  = idx >> 16;

    const int VL  = vlg[b];
    const int nkt = (VL + KTILE - 1) / KTILE;
    const int tps = (nkt + ns - 1) / ns;
    const int nv  = (nkt + tps - 1) / tps;            // valid splits

    float M = -1e30f, den = 0.f;
    f32x4 acc = {0.f, 0.f, 0.f, 0.f};
    for (int s = 0; s < nv; ++s) {
        const size_t row = (size_t)(s * NB + b) * TQ + q;
        float2 ml = *(const float2*)&wsml[row * 2];
        float Mn = fmaxf(M, ml.x);
        float c  = fast_exp2(M - Mn);
        float w  = fast_exp2(ml.x - Mn);
        f32x4 ov = *(const f32x4*)&wso[row * DVV + d4 * 4];
        acc = acc * c + ov * w;
        den = den * c + w * ml.y;
        M = Mn;
    }
    const float inv = 1.0f / den;
    f32x4 r = acc * inv;
    *(f32x4*)&outg[((size_t)b * TQ + q) * DVV + d4 * 4] = r;
}

extern "C" void kernel_launch(void* const* d_in, const int* in_sizes, int n_in,
                              void* d_out, int out_size, void* d_ws, size_t ws_size,
                              hipStream_t stream) {
    const float* q  = (const float*)d_in[0];
    const float* k  = (const float*)d_in[1];
    const float* v  = (const float*)d_in[2];
    const int*   vl = (const int*)d_in[3];
    float* out = (float*)d_out;

    const size_t o_elems  = (size_t)NB * TQ * DVV;       // per split
    const size_t ml_elems = (size_t)NB * TQ * 2;         // per split
    const size_t per_split = (o_elems + ml_elems) * sizeof(float);

    int ns = (ws_size >= 2 * per_split) ? 2 : 1;

    float* wso  = (float*)d_ws;
    float* wsml = wso + (size_t)ns * o_elems;

    dim3 grid(NB * (TQ / QTILE), ns);
    hipLaunchKernelGGL(attn_fwd, grid, dim3(256), 0, stream,
                       q, k, v, vl, out, wso, wsml, ns);

    if (ns > 1) {
        dim3 cgrid((NB * TQ * (DVV / 4)) / 256);
        hipLaunchKernelGGL(attn_combine, cgrid, dim3(256), 0, stream,
                           wso, wsml, vl, out, ns);
    }
}

// Round 6
// 73.037 us; speedup vs baseline: 1.5632x; 1.3450x over previous
//
#include <hip/hip_runtime.h>
#include <math.h>

#define NB 16
#define TQ 2048
#define TK 2048
#define DD 128
#define DVV 128

constexpr int QTILE = 64;   // q rows per block (4 waves x 16)
constexpr int KTILE = 32;   // k/v rows per staged tile
#define PSTR 40             // halfs, 80B row stride (P tile)

typedef __attribute__((ext_vector_type(8))) _Float16 half8;
typedef __attribute__((ext_vector_type(4))) _Float16 half4;
typedef __attribute__((ext_vector_type(4))) float f32x4;

__device__ inline float fast_exp2(float x) {
#if __has_builtin(__builtin_amdgcn_exp2f)
    return __builtin_amdgcn_exp2f(x);
#else
    return exp2f(x);
#endif
}
__device__ inline void setprio1() { __builtin_amdgcn_s_setprio(1); }
__device__ inline void setprio0() { __builtin_amdgcn_s_setprio(0); }

// async global->LDS DMA, 16B per lane; LDS dest is wave-uniform base + lane*16
__device__ inline void glds16(const _Float16* g, _Float16* l) {
    __builtin_amdgcn_global_load_lds(
        (const __attribute__((address_space(1))) void*)g,
        (__attribute__((address_space(3))) void*)l, 16, 0, 0);
}

// ---------------- pre-pass: fp32 K/V -> fp16, fragment-packed per 32-row tile ----
// K tile layout: slot(kr,kc) = ct*4096 + c*1024 + (lhi*16+l15)*16 + j*2 bytes
//   (ct=kr>>4, l15=kr&15, c=kc>>5, lhi=(kc>>3)&3, j=kc&7)
// V tile layout: slot(dv,k) = n*1024 + (lhi*16+l15)*16 + j*2 bytes
//   (n=dv>>4, l15=dv&15, lhi=k>>3, j=k&7)   [transposed: fragment = 8 consecutive k]
__global__ __launch_bounds__(256)
void repack(const float* __restrict__ kg, const float* __restrict__ vg,
            const int* __restrict__ vlg,
            _Float16* __restrict__ Kpk, _Float16* __restrict__ Vpk)
{
    const int bt = blockIdx.x;          // b*64 + t
    const int b = bt >> 6, t = bt & 63;
    if (t * KTILE >= vlg[b]) return;    // tile fully masked: never read
    const int tid = threadIdx.x;

    __shared__ float Vlds[32][129];

    // ---- K: direct, output-coalesced (2 x 16B slots per thread) ----
    const float* kin = kg + ((size_t)b * TK + t * KTILE) * DD;
    _Float16* kout = Kpk + ((size_t)bt << 12);
#pragma unroll
    for (int pp = 0; pp < 2; ++pp) {
        int s = tid + pp * 256;
        int ct = s >> 8, c = (s >> 6) & 3, ln = s & 63;
        int kr = ct * 16 + (ln & 15), kc = c * 32 + ((ln >> 4) & 3) * 8;
        const float* ip = kin + kr * DD + kc;
        float4 f0 = *(const float4*)ip;
        float4 f1 = *(const float4*)(ip + 4);
        half8 h;
        h[0] = (_Float16)f0.x; h[1] = (_Float16)f0.y;
        h[2] = (_Float16)f0.z; h[3] = (_Float16)f0.w;
        h[4] = (_Float16)f1.x; h[5] = (_Float16)f1.y;
        h[6] = (_Float16)f1.z; h[7] = (_Float16)f1.w;
        *(half8*)(kout + (size_t)s * 8) = h;
    }

    // ---- V: stage fp32 tile in LDS, then packed-transposed coalesced write ----
    const float* vin = vg + ((size_t)b * TK + t * KTILE) * DVV;
#pragma unroll
    for (int pp = 0; pp < 4; ++pp) {
        int idx = tid + pp * 256;             // 1024 float4 = 32x128
        int r = idx >> 5, c4 = (idx & 31) * 4;
        float4 f = *(const float4*)(vin + r * DVV + c4);
        Vlds[r][c4 + 0] = f.x; Vlds[r][c4 + 1] = f.y;
        Vlds[r][c4 + 2] = f.z; Vlds[r][c4 + 3] = f.w;
    }
    __syncthreads();
    _Float16* vout = Vpk + ((size_t)bt << 12);
#pragma unroll
    for (int pp = 0; pp < 2; ++pp) {
        int s = tid + pp * 256;
        int n = s >> 6, ln = s & 63;
        int dv = n * 16 + (ln & 15), k0 = ((ln >> 4) & 3) * 8;
        half8 h;
#pragma unroll
        for (int j = 0; j < 8; ++j)
            h[j] = (_Float16)Vlds[k0 + j][dv];
        *(half8*)(vout + (size_t)s * 8) = h;
    }
}

// ---------------- attention pass: one (b, q-tile, k-split) per block ----------------
__global__ __launch_bounds__(256, 4)
void attn_fwd(const float* __restrict__ qg,
              const _Float16* __restrict__ Kpk, const _Float16* __restrict__ Vpk,
              const int* __restrict__ vlg,
              float* __restrict__ outg, float* __restrict__ wso,
              float* __restrict__ wsml, int ns)
{
    __shared__ _Float16 Kb[2][4096];          // 2 x 8192 B, fragment-packed
    __shared__ _Float16 Vb[2][4096];          // 2 x 8192 B
    __shared__ _Float16 Plds[4][16][PSTR];    // 5120 B        total 37888 B

    const int tid  = threadIdx.x;
    const int wid  = tid >> 6;
    const int lane = tid & 63;
    const int l15  = lane & 15;
    const int lhi  = lane >> 4;

    const int bid   = blockIdx.x;
    const int b     = bid & (NB - 1);
    const int qbase = (bid >> 4) * QTILE;
    const int sp    = blockIdx.y;

    const int VL  = vlg[b];
    const int nkt = (VL + KTILE - 1) / KTILE;
    const int tps = (nkt + ns - 1) / ns;
    const int t0  = sp * tps;
    const int t1  = min(nkt, t0 + tps);
    if (t0 >= t1) return;                     // empty split (before any barrier)

    const _Float16* ktb = Kpk + ((size_t)(b * 64) << 12);
    const _Float16* vtb = Vpk + ((size_t)(b * 64) << 12);

    // ---- Q fragments, scale * log2e folded (softmax in log2 domain) ----
    half8 qf[4];
    {
        const float scale = 0.08838834764831845f * 1.4426950408889634f;
        const int qrow = qbase + wid * 16 + l15;
        const float* qp = qg + (size_t)(b * TQ + qrow) * DD + lhi * 8;
#pragma unroll
        for (int c = 0; c < 4; ++c) {
            float4 f0 = *(const float4*)(qp + c * 32);
            float4 f1 = *(const float4*)(qp + c * 32 + 4);
            half8 t;
            t[0] = (_Float16)(f0.x * scale); t[1] = (_Float16)(f0.y * scale);
            t[2] = (_Float16)(f0.z * scale); t[3] = (_Float16)(f0.w * scale);
            t[4] = (_Float16)(f1.x * scale); t[5] = (_Float16)(f1.y * scale);
            t[6] = (_Float16)(f1.z * scale); t[7] = (_Float16)(f1.w * scale);
            qf[c] = t;
        }
    }

    // ---- DMA staging: 4 x global_load_lds_dwordx4 per wave, linear LDS ----
    auto STAGE = [&](int buf, int t) {
        const _Float16* kp = ktb + ((size_t)t << 12) + wid * 1024 + lane * 8;
        const _Float16* vp = vtb + ((size_t)t << 12) + wid * 1024 + lane * 8;
        glds16(kp,       &Kb[buf][wid * 1024]);
        glds16(kp + 512, &Kb[buf][wid * 1024 + 512]);
        glds16(vp,       &Vb[buf][wid * 1024]);
        glds16(vp + 512, &Vb[buf][wid * 1024 + 512]);
    };

    float m_i = -INFINITY, l_i = 0.f;
    f32x4 o[8];
#pragma unroll
    for (int n = 0; n < 8; ++n) { f32x4 z = {0.f, 0.f, 0.f, 0.f}; o[n] = z; }

    STAGE(0, t0);
    int cur = 0;
    for (int t = t0; t < t1; ++t) {
        const int kb = t * KTILE;
        const bool pre = (t + 1 < t1);
        if (pre) STAGE(cur ^ 1, t + 1);       // fire-and-forget next tile

        // counted wait: newest 4 (next tile) stay in flight; raw barrier (no drain)
        if (pre) asm volatile("s_waitcnt vmcnt(4)\ns_barrier" ::: "memory");
        else     asm volatile("s_waitcnt vmcnt(0)\ns_barrier" ::: "memory");

        const half8* kp = (const half8*)&Kb[cur][0];
        const half8* vp = (const half8*)&Vb[cur][0];

        // ---- S^T = K Q^T : rows k (ct*16 + lhi*4+r), cols q (l15) ----
        f32x4 sc[2];
        setprio1();
#pragma unroll
        for (int ct = 0; ct < 2; ++ct) {
            f32x4 z = {0.f, 0.f, 0.f, 0.f};
            sc[ct] = z;
#pragma unroll
            for (int c = 0; c < 4; ++c) {
                half8 kf = kp[ct * 256 + c * 64 + lane];   // conflict-free: lane*16B
                sc[ct] = __builtin_amdgcn_mfma_f32_16x16x32_f16(kf, qf[c], sc[ct], 0, 0, 0);
            }
        }
        setprio0();

        // ---- mask k rows >= VL (boundary tile only) ----
        if (kb + KTILE > VL) {
#pragma unroll
            for (int ct = 0; ct < 2; ++ct) {
                const int kg = kb + ct * 16 + lhi * 4;
#pragma unroll
                for (int r = 0; r < 4; ++r)
                    if (kg + r >= VL) sc[ct][r] = -1e30f;
            }
        }

        // ---- per-lane online softmax (q = l15): 8 in-lane + 2 shuffles ----
        float mx = sc[0][0];
#pragma unroll
        for (int ct = 0; ct < 2; ++ct)
#pragma unroll
            for (int r = 0; r < 4; ++r) mx = fmaxf(mx, sc[ct][r]);
        mx = fmaxf(mx, __shfl_xor(mx, 16));
        mx = fmaxf(mx, __shfl_xor(mx, 32));

        const bool skip = __all(mx <= m_i + 8.0f);   // defer-max (log2 domain)
        const float mnew = skip ? m_i : fmaxf(m_i, mx);

        float p[8];
        float sum = 0.f;
#pragma unroll
        for (int ct = 0; ct < 2; ++ct)
#pragma unroll
            for (int r = 0; r < 4; ++r) {
                float e = fast_exp2(sc[ct][r] - mnew);
                p[ct * 4 + r] = e;
                sum += e;
            }
        sum += __shfl_xor(sum, 16);
        sum += __shfl_xor(sum, 32);

        // write P^T-layout [q][k]
#pragma unroll
        for (int ct = 0; ct < 2; ++ct) {
            half4 ph;
            ph[0] = (_Float16)p[ct * 4 + 0]; ph[1] = (_Float16)p[ct * 4 + 1];
            ph[2] = (_Float16)p[ct * 4 + 2]; ph[3] = (_Float16)p[ct * 4 + 3];
            *(half4*)&Plds[wid][l15][ct * 16 + lhi * 4] = ph;
        }

        if (skip) {
            l_i += sum;
        } else {
            const float corr = fast_exp2(m_i - mnew);
            l_i = l_i * corr + sum;
            m_i = mnew;
            float cr[4];
#pragma unroll
            for (int r = 0; r < 4; ++r)
                cr[r] = __shfl(corr, (lane & 48) | (lhi * 4 + r));
#pragma unroll
            for (int n = 0; n < 8; ++n)
#pragma unroll
                for (int r = 0; r < 4; ++r) o[n][r] *= cr[r];
        }

        // ---- O += P V ----
        half8 pa = *(const half8*)&Plds[wid][l15][lhi * 8];
        setprio1();
#pragma unroll
        for (int n = 0; n < 8; ++n) {
            half8 vb = vp[n * 64 + lane];                  // conflict-free: lane*16B
            o[n] = __builtin_amdgcn_mfma_f32_16x16x32_f16(pa, vb, o[n], 0, 0, 0);
        }
        setprio0();

        // reads of cur buf complete before anyone DMAs over it next iter
        asm volatile("s_waitcnt lgkmcnt(0)\ns_barrier" ::: "memory");
        cur ^= 1;
    }

    if (ns == 1) {
        float li4[4];
#pragma unroll
        for (int r = 0; r < 4; ++r) {
            float lr = __shfl(l_i, (lane & 48) | (lhi * 4 + r));
            li4[r] = 1.0f / lr;
        }
#pragma unroll
        for (int r = 0; r < 4; ++r) {
            const int qrow = qbase + wid * 16 + lhi * 4 + r;
            float* op = outg + (size_t)(b * TQ + qrow) * DVV + l15;
#pragma unroll
            for (int n = 0; n < 8; ++n)
                op[n * 16] = o[n][r] * li4[r];
        }
    } else {
        if (lhi == 0) {
            float2 ml = make_float2(m_i, l_i);
            *(float2*)&wsml[((size_t)(sp * NB + b) * TQ + qbase + wid * 16 + l15) * 2] = ml;
        }
        float* po = wso + ((size_t)(sp * NB + b) * TQ + qbase + wid * 16) * DVV;
#pragma unroll
        for (int r = 0; r < 4; ++r)
#pragma unroll
            for (int n = 0; n < 8; ++n)
                po[(lhi * 4 + r) * DVV + n * 16 + l15] = o[n][r];
    }
}

// ---------------- combine pass: softmax-weighted merge of splits ----------------
__global__ __launch_bounds__(256)
void attn_combine(const float* __restrict__ wso, const float* __restrict__ wsml,
                  const int* __restrict__ vlg, float* __restrict__ outg, int ns)
{
    const int idx = blockIdx.x * 256 + threadIdx.x;   // B*TQ*(DVV/4)
    const int d4 = idx & 31;
    const int q  = (idx >> 5) & (TQ - 1);
    const int b  = idx >> 16;

    const int VL  = vlg[b];
    const int nkt = (VL + KTILE - 1) / KTILE;
    const int tps = (nkt + ns - 1) / ns;
    const int nv  = (nkt + tps - 1) / tps;            // valid splits

    float M = -1e30f, den = 0.f;
    f32x4 acc = {0.f, 0.f, 0.f, 0.f};
    for (int s = 0; s < nv; ++s) {
        const size_t row = (size_t)(s * NB + b) * TQ + q;
        float2 ml = *(const float2*)&wsml[row * 2];
        float Mn = fmaxf(M, ml.x);
        float c  = fast_exp2(M - Mn);
        float w  = fast_exp2(ml.x - Mn);
        f32x4 ov = *(const f32x4*)&wso[row * DVV + d4 * 4];
        acc = acc * c + ov * w;
        den = den * c + w * ml.y;
        M = Mn;
    }
    const float inv = 1.0f / den;
    f32x4 r = acc * inv;
    *(f32x4*)&outg[((size_t)b * TQ + q) * DVV + d4 * 4] = r;
}

extern "C" void kernel_launch(void* const* d_in, const int* in_sizes, int n_in,
                              void* d_out, int out_size, void* d_ws, size_t ws_size,
                              hipStream_t stream) {
    const float* q  = (const float*)d_in[0];
    const float* k  = (const float*)d_in[1];
    const float* v  = (const float*)d_in[2];
    const int*   vl = (const int*)d_in[3];
    float* out = (float*)d_out;

    const size_t pk_elems = (size_t)NB * 64 * 4096;      // halfs per packed tensor
    const size_t pk_bytes = pk_elems * sizeof(_Float16); // 8.39 MB
    const size_t o_elems  = (size_t)NB * TQ * DVV;
    const size_t ml_elems = (size_t)NB * TQ * 2;
    const size_t per_split = (o_elems + ml_elems) * sizeof(float);

    int ns = (ws_size >= 2 * pk_bytes + 2 * per_split) ? 2 : 1;

    _Float16* Kpk = (_Float16*)d_ws;
    _Float16* Vpk = Kpk + pk_elems;
    float* wso  = (float*)(Vpk + pk_elems);
    float* wsml = wso + (size_t)ns * o_elems;

    hipLaunchKernelGGL(repack, dim3(NB * 64), dim3(256), 0, stream,
                       k, v, vl, Kpk, Vpk);

    dim3 grid(NB * (TQ / QTILE), ns);
    hipLaunchKernelGGL(attn_fwd, grid, dim3(256), 0, stream,
                       q, Kpk, Vpk, vl, out, wso, wsml, ns);

    if (ns > 1) {
        dim3 cgrid((NB * TQ * (DVV / 4)) / 256);
        hipLaunchKernelGGL(attn_combine, cgrid, dim3(256), 0, stream,
                           wso, wsml, vl, out, ns);
    }
}

// Round 7
// 71.708 us; speedup vs baseline: 1.5921x; 1.0185x over previous
//
#include <hip/hip_runtime.h>
#include <math.h>

#define NB 16
#define TQ 2048
#define TK 2048
#define DD 128
#define DVV 128

constexpr int QTILE = 128;  // q rows per block (8 waves x 16)
constexpr int KTILE = 32;   // k/v rows per staged tile
#define PSTR 40             // halfs, 80B row stride (P tile)

typedef __attribute__((ext_vector_type(8))) _Float16 half8;
typedef __attribute__((ext_vector_type(4))) _Float16 half4;
typedef __attribute__((ext_vector_type(4))) float f32x4;

__device__ inline float fast_exp2(float x) {
#if __has_builtin(__builtin_amdgcn_exp2f)
    return __builtin_amdgcn_exp2f(x);
#else
    return exp2f(x);
#endif
}
__device__ inline void setprio1() { __builtin_amdgcn_s_setprio(1); }
__device__ inline void setprio0() { __builtin_amdgcn_s_setprio(0); }

// async global->LDS DMA, 16B per lane; LDS dest is wave-uniform base + lane*16
__device__ inline void glds16(const _Float16* g, _Float16* l) {
    __builtin_amdgcn_global_load_lds(
        (const __attribute__((address_space(1))) void*)g,
        (__attribute__((address_space(3))) void*)l, 16, 0, 0);
}

// ---------------- pre-pass: fp32 K/V -> fp16, fragment-packed per 32-row tile ----
// K tile layout: slot(kr,kc): ct=kr>>4, l15=kr&15, c=kc>>5, lhi=(kc>>3)&3, j=kc&7
//   -> halfs offset ct*2048 + c*512 + (lhi*16+l15)*8 + j
// V tile layout (transposed): n=dv>>4, l15=dv&15, lhi=k>>3, j=k&7
//   -> halfs offset n*512 + (lhi*16+l15)*8 + j
__global__ __launch_bounds__(256)
void repack(const float* __restrict__ kg, const float* __restrict__ vg,
            const int* __restrict__ vlg,
            _Float16* __restrict__ Kpk, _Float16* __restrict__ Vpk)
{
    const int bt = blockIdx.x;          // b*64 + t
    const int b = bt >> 6, t = bt & 63;
    if (t * KTILE >= vlg[b]) return;    // tile fully masked: never read
    const int tid = threadIdx.x;

    __shared__ float Vlds[32][129];

    // ---- K: direct, output-coalesced (2 x 16B slots per thread) ----
    const float* kin = kg + ((size_t)b * TK + t * KTILE) * DD;
    _Float16* kout = Kpk + ((size_t)bt << 12);
#pragma unroll
    for (int pp = 0; pp < 2; ++pp) {
        int s = tid + pp * 256;
        int ct = s >> 8, c = (s >> 6) & 3, ln = s & 63;
        int kr = ct * 16 + (ln & 15), kc = c * 32 + ((ln >> 4) & 3) * 8;
        const float* ip = kin + kr * DD + kc;
        float4 f0 = *(const float4*)ip;
        float4 f1 = *(const float4*)(ip + 4);
        half8 h;
        h[0] = (_Float16)f0.x; h[1] = (_Float16)f0.y;
        h[2] = (_Float16)f0.z; h[3] = (_Float16)f0.w;
        h[4] = (_Float16)f1.x; h[5] = (_Float16)f1.y;
        h[6] = (_Float16)f1.z; h[7] = (_Float16)f1.w;
        *(half8*)(kout + (size_t)s * 8) = h;
    }

    // ---- V: stage fp32 tile in LDS, then packed-transposed coalesced write ----
    const float* vin = vg + ((size_t)b * TK + t * KTILE) * DVV;
#pragma unroll
    for (int pp = 0; pp < 4; ++pp) {
        int idx = tid + pp * 256;             // 1024 float4 = 32x128
        int r = idx >> 5, c4 = (idx & 31) * 4;
        float4 f = *(const float4*)(vin + r * DVV + c4);
        Vlds[r][c4 + 0] = f.x; Vlds[r][c4 + 1] = f.y;
        Vlds[r][c4 + 2] = f.z; Vlds[r][c4 + 3] = f.w;
    }
    __syncthreads();
    _Float16* vout = Vpk + ((size_t)bt << 12);
#pragma unroll
    for (int pp = 0; pp < 2; ++pp) {
        int s = tid + pp * 256;
        int n = s >> 6, ln = s & 63;
        int dv = n * 16 + (ln & 15), k0 = ((ln >> 4) & 3) * 8;
        half8 h;
#pragma unroll
        for (int j = 0; j < 8; ++j)
            h[j] = (_Float16)Vlds[k0 + j][dv];
        *(half8*)(vout + (size_t)s * 8) = h;
    }
}

// ---------------- attention pass: one (b, q-tile, k-split) per block ----------------
__global__ __launch_bounds__(512, 6)
void attn_fwd(const float* __restrict__ qg,
              const _Float16* __restrict__ Kpk, const _Float16* __restrict__ Vpk,
              const int* __restrict__ vlg,
              float* __restrict__ outg, _Float16* __restrict__ wso,
              float* __restrict__ wsml, int ns)
{
    __shared__ _Float16 Kb[2][4096];          // 2 x 8192 B, fragment-packed
    __shared__ _Float16 Vb[2][4096];          // 2 x 8192 B
    __shared__ _Float16 Plds[8][16][PSTR];    // 10240 B       total 43008 B

    const int tid  = threadIdx.x;
    const int wid  = tid >> 6;                // 0..7
    const int lane = tid & 63;
    const int l15  = lane & 15;
    const int lhi  = lane >> 4;

    const int bid   = blockIdx.x;             // NB * (TQ/128) = 256
    const int b     = bid & (NB - 1);
    const int qbase = (bid >> 4) * QTILE;
    const int sp    = blockIdx.y;

    const int VL  = vlg[b];
    const int nkt = (VL + KTILE - 1) / KTILE;
    const int tps = (nkt + ns - 1) / ns;
    const int t0  = sp * tps;
    const int t1  = min(nkt, t0 + tps);
    if (t0 >= t1) return;                     // empty split (before any barrier)

    const _Float16* ktb = Kpk + ((size_t)(b * 64) << 12);
    const _Float16* vtb = Vpk + ((size_t)(b * 64) << 12);

    // ---- Q fragments, scale * log2e folded (softmax in log2 domain) ----
    half8 qf[4];
    {
        const float scale = 0.08838834764831845f * 1.4426950408889634f;
        const int qrow = qbase + wid * 16 + l15;
        const float* qp = qg + (size_t)(b * TQ + qrow) * DD + lhi * 8;
#pragma unroll
        for (int c = 0; c < 4; ++c) {
            float4 f0 = *(const float4*)(qp + c * 32);
            float4 f1 = *(const float4*)(qp + c * 32 + 4);
            half8 t;
            t[0] = (_Float16)(f0.x * scale); t[1] = (_Float16)(f0.y * scale);
            t[2] = (_Float16)(f0.z * scale); t[3] = (_Float16)(f0.w * scale);
            t[4] = (_Float16)(f1.x * scale); t[5] = (_Float16)(f1.y * scale);
            t[6] = (_Float16)(f1.z * scale); t[7] = (_Float16)(f1.w * scale);
            qf[c] = t;
        }
    }

    // ---- DMA staging: waves 0-3 stage K quarters, waves 4-7 stage V quarters ----
    const int qtr = wid & 3;
    auto STAGE = [&](int buf, int t) {
        const _Float16* src = ((wid < 4) ? ktb : vtb)
                              + ((size_t)t << 12) + qtr * 1024 + lane * 8;
        _Float16* dst = (wid < 4) ? &Kb[buf][qtr * 1024] : &Vb[buf][qtr * 1024];
        glds16(src, dst);
        glds16(src + 512, dst + 512);
    };

    float m_i = -INFINITY, l_i = 0.f;
    f32x4 o[8];
#pragma unroll
    for (int n = 0; n < 8; ++n) { f32x4 z = {0.f, 0.f, 0.f, 0.f}; o[n] = z; }

    STAGE(0, t0);
    int cur = 0;
    for (int t = t0; t < t1; ++t) {
        const int kb = t * KTILE;
        const bool pre = (t + 1 < t1);
        if (pre) STAGE(cur ^ 1, t + 1);       // fire-and-forget next tile

        // counted wait: newest 2 (next tile) stay in flight; raw barrier (no drain)
        if (pre) asm volatile("s_waitcnt vmcnt(2)\ns_barrier" ::: "memory");
        else     asm volatile("s_waitcnt vmcnt(0)\ns_barrier" ::: "memory");

        const half8* kp = (const half8*)&Kb[cur][0];
        const half8* vp = (const half8*)&Vb[cur][0];

        // ---- S^T = K Q^T : rows k (ct*16 + lhi*4+r), cols q (l15) ----
        f32x4 sc[2];
        setprio1();
#pragma unroll
        for (int ct = 0; ct < 2; ++ct) {
            f32x4 z = {0.f, 0.f, 0.f, 0.f};
            sc[ct] = z;
#pragma unroll
            for (int c = 0; c < 4; ++c) {
                half8 kf = kp[ct * 256 + c * 64 + lane];   // conflict-free: lane*16B
                sc[ct] = __builtin_amdgcn_mfma_f32_16x16x32_f16(kf, qf[c], sc[ct], 0, 0, 0);
            }
        }
        setprio0();

        // ---- mask k rows >= VL (boundary tile only) ----
        if (kb + KTILE > VL) {
#pragma unroll
            for (int ct = 0; ct < 2; ++ct) {
                const int kg = kb + ct * 16 + lhi * 4;
#pragma unroll
                for (int r = 0; r < 4; ++r)
                    if (kg + r >= VL) sc[ct][r] = -1e30f;
            }
        }

        // ---- per-lane online softmax (q = l15): 8 in-lane + 2 shuffles ----
        float mx = sc[0][0];
#pragma unroll
        for (int ct = 0; ct < 2; ++ct)
#pragma unroll
            for (int r = 0; r < 4; ++r) mx = fmaxf(mx, sc[ct][r]);
        mx = fmaxf(mx, __shfl_xor(mx, 16));
        mx = fmaxf(mx, __shfl_xor(mx, 32));

        const bool skip = __all(mx <= m_i + 8.0f);   // defer-max (log2 domain)
        const float mnew = skip ? m_i : fmaxf(m_i, mx);

        float p[8];
        float sum = 0.f;
#pragma unroll
        for (int ct = 0; ct < 2; ++ct)
#pragma unroll
            for (int r = 0; r < 4; ++r) {
                float e = fast_exp2(sc[ct][r] - mnew);
                p[ct * 4 + r] = e;
                sum += e;
            }
        sum += __shfl_xor(sum, 16);
        sum += __shfl_xor(sum, 32);

        // write P^T-layout [q][k]
#pragma unroll
        for (int ct = 0; ct < 2; ++ct) {
            half4 ph;
            ph[0] = (_Float16)p[ct * 4 + 0]; ph[1] = (_Float16)p[ct * 4 + 1];
            ph[2] = (_Float16)p[ct * 4 + 2]; ph[3] = (_Float16)p[ct * 4 + 3];
            *(half4*)&Plds[wid][l15][ct * 16 + lhi * 4] = ph;
        }

        if (skip) {
            l_i += sum;
        } else {
            const float corr = fast_exp2(m_i - mnew);
            l_i = l_i * corr + sum;
            m_i = mnew;
            float cr[4];
#pragma unroll
            for (int r = 0; r < 4; ++r)
                cr[r] = __shfl(corr, (lane & 48) | (lhi * 4 + r));
#pragma unroll
            for (int n = 0; n < 8; ++n)
#pragma unroll
                for (int r = 0; r < 4; ++r) o[n][r] *= cr[r];
        }

        // ---- O += P V ----
        half8 pa = *(const half8*)&Plds[wid][l15][lhi * 8];
        setprio1();
#pragma unroll
        for (int n = 0; n < 8; ++n) {
            half8 vb = vp[n * 64 + lane];                  // conflict-free: lane*16B
            o[n] = __builtin_amdgcn_mfma_f32_16x16x32_f16(pa, vb, o[n], 0, 0, 0);
        }
        setprio0();

        // reads of cur buf complete before anyone DMAs over it next iter
        asm volatile("s_waitcnt lgkmcnt(0)\ns_barrier" ::: "memory");
        cur ^= 1;
    }

    if (ns == 1) {
        float li4[4];
#pragma unroll
        for (int r = 0; r < 4; ++r) {
            float lr = __shfl(l_i, (lane & 48) | (lhi * 4 + r));
            li4[r] = 1.0f / lr;
        }
#pragma unroll
        for (int r = 0; r < 4; ++r) {
            const int qrow = qbase + wid * 16 + lhi * 4 + r;
            float* op = outg + (size_t)(b * TQ + qrow) * DVV + l15;
#pragma unroll
            for (int n = 0; n < 8; ++n)
                op[n * 16] = o[n][r] * li4[r];
        }
    } else {
        if (lhi == 0) {
            float2 ml = make_float2(m_i, l_i);
            *(float2*)&wsml[((size_t)(sp * NB + b) * TQ + qbase + wid * 16 + l15) * 2] = ml;
        }
        _Float16* po = wso + ((size_t)(sp * NB + b) * TQ + qbase + wid * 16) * DVV;
#pragma unroll
        for (int r = 0; r < 4; ++r)
#pragma unroll
            for (int n = 0; n < 8; ++n)
                po[(lhi * 4 + r) * DVV + n * 16 + l15] = (_Float16)o[n][r];
    }
}

// ---------------- combine pass: softmax-weighted merge of splits ----------------
__global__ __launch_bounds__(256)
void attn_combine(const _Float16* __restrict__ wso, const float* __restrict__ wsml,
                  const int* __restrict__ vlg, float* __restrict__ outg, int ns)
{
    const int idx = blockIdx.x * 256 + threadIdx.x;   // NB*TQ*16, 8 elems/thread
    const int d8 = idx & 15;
    const int q  = (idx >> 4) & (TQ - 1);
    const int b  = idx >> 15;

    const int VL  = vlg[b];
    const int nkt = (VL + KTILE - 1) / KTILE;
    const int tps = (nkt + ns - 1) / ns;
    const int nv  = (nkt + tps - 1) / tps;            // valid splits

    float M = -1e30f, den = 0.f;
    float acc[8] = {0.f, 0.f, 0.f, 0.f, 0.f, 0.f, 0.f, 0.f};
    for (int s = 0; s < nv; ++s) {
        const size_t row = (size_t)(s * NB + b) * TQ + q;
        float2 ml = *(const float2*)&wsml[row * 2];
        float Mn = fmaxf(M, ml.x);
        float c  = fast_exp2(M - Mn);
        float w  = fast_exp2(ml.x - Mn);
        half8 ov = *(const half8*)&wso[row * DVV + d8 * 8];
#pragma unroll
        for (int j = 0; j < 8; ++j)
            acc[j] = acc[j] * c + (float)ov[j] * w;
        den = den * c + w * ml.y;
        M = Mn;
    }
    const float inv = 1.0f / den;
    float* op = outg + ((size_t)b * TQ + q) * DVV + d8 * 8;
    f32x4 r0 = {acc[0] * inv, acc[1] * inv, acc[2] * inv, acc[3] * inv};
    f32x4 r1 = {acc[4] * inv, acc[5] * inv, acc[6] * inv, acc[7] * inv};
    *(f32x4*)op = r0;
    *(f32x4*)(op + 4) = r1;
}

extern "C" void kernel_launch(void* const* d_in, const int* in_sizes, int n_in,
                              void* d_out, int out_size, void* d_ws, size_t ws_size,
                              hipStream_t stream) {
    const float* q  = (const float*)d_in[0];
    const float* k  = (const float*)d_in[1];
    const float* v  = (const float*)d_in[2];
    const int*   vl = (const int*)d_in[3];
    float* out = (float*)d_out;

    const size_t pk_elems = (size_t)NB * 64 * 4096;        // halfs per packed tensor
    const size_t pk_bytes = 2 * pk_elems * sizeof(_Float16); // K + V = 16.78 MB
    const size_t o_elems  = (size_t)NB * TQ * DVV;         // per split (fp16)
    const size_t ml_elems = (size_t)NB * TQ * 2;           // per split (fp32)
    const size_t per_split = o_elems * sizeof(_Float16) + ml_elems * sizeof(float);

    int ns = 1;
    if (ws_size >= pk_bytes + 4 * per_split) ns = 4;
    else if (ws_size >= pk_bytes + 2 * per_split) ns = 2;

    _Float16* Kpk = (_Float16*)d_ws;
    _Float16* Vpk = Kpk + pk_elems;
    _Float16* wso  = Vpk + pk_elems;
    float*    wsml = (float*)(wso + (size_t)ns * o_elems);

    hipLaunchKernelGGL(repack, dim3(NB * 64), dim3(256), 0, stream,
                       k, v, vl, Kpk, Vpk);

    dim3 grid(NB * (TQ / QTILE), ns);
    hipLaunchKernelGGL(attn_fwd, grid, dim3(512), 0, stream,
                       q, Kpk, Vpk, vl, out, wso, wsml, ns);

    if (ns > 1) {
        dim3 cgrid((NB * TQ * 16) / 256);
        hipLaunchKernelGGL(attn_combine, cgrid, dim3(256), 0, stream,
                           wso, wsml, vl, out, ns);
    }
}